// Round 3
// baseline (137.128 us; speedup 1.0000x reference)
//
#include <hip/hip_runtime.h>
#include <stdint.h>

// ---------------------------------------------------------------------------
// CritiGraph distance kernel: bit-exact reproduction of the JAX reference
// (jax_threefry_partitionable=True path, verified absmax 0.0).
//
// Round-5: MEASUREMENT ROUND. Kernel body identical to round-4 (LDS
// transpose, 116.95 us). kernel_launch enqueues the kernel TWICE
// (idempotent: reads only inputs, writes deterministic values) so that
//   dur_us = OH + 2*K   vs previous  116.95 = OH + K
// separates the fixed harness overhead OH (re-poison fills, ~43 us each,
// seen as __amd_rocclr_fillBufferAligned in rocprof) from the true kernel
// time K. Decision next round: K <= ~16 us -> controllable floor reached;
// K ~ 31 us -> occupancy/overlap restructure.
// ---------------------------------------------------------------------------

#define H_   16
#define TP_  16
#define K_   16
#define T_   2048
#define NC   513                       // 2*H*K + 1

typedef float f32x4 __attribute__((ext_vector_type(4)));

struct TFPair { uint32_t a, b; };

__host__ __device__ constexpr uint32_t rotl32(uint32_t x, int r) {
  return (x << r) | (x >> (32 - r));
}

__host__ __device__ constexpr TFPair tf2x32(uint32_t k0, uint32_t k1,
                                            uint32_t x0, uint32_t x1) {
  uint32_t ks0 = k0, ks1 = k1, ks2 = k0 ^ k1 ^ 0x1BD11BDAu;
  x0 += ks0; x1 += ks1;
  x0 += x1; x1 = rotl32(x1, 13); x1 ^= x0;
  x0 += x1; x1 = rotl32(x1, 15); x1 ^= x0;
  x0 += x1; x1 = rotl32(x1, 26); x1 ^= x0;
  x0 += x1; x1 = rotl32(x1,  6); x1 ^= x0;
  x0 += ks1; x1 += ks2 + 1u;
  x0 += x1; x1 = rotl32(x1, 17); x1 ^= x0;
  x0 += x1; x1 = rotl32(x1, 29); x1 ^= x0;
  x0 += x1; x1 = rotl32(x1, 16); x1 ^= x0;
  x0 += x1; x1 = rotl32(x1, 24); x1 ^= x0;
  x0 += ks2; x1 += ks0 + 2u;
  x0 += x1; x1 = rotl32(x1, 13); x1 ^= x0;
  x0 += x1; x1 = rotl32(x1, 15); x1 ^= x0;
  x0 += x1; x1 = rotl32(x1, 26); x1 ^= x0;
  x0 += x1; x1 = rotl32(x1,  6); x1 ^= x0;
  x0 += ks0; x1 += ks1 + 3u;
  x0 += x1; x1 = rotl32(x1, 17); x1 ^= x0;
  x0 += x1; x1 = rotl32(x1, 29); x1 ^= x0;
  x0 += x1; x1 = rotl32(x1, 16); x1 ^= x0;
  x0 += x1; x1 = rotl32(x1, 24); x1 ^= x0;
  x0 += ks1; x1 += ks2 + 4u;
  x0 += x1; x1 = rotl32(x1, 13); x1 ^= x0;
  x0 += x1; x1 = rotl32(x1, 15); x1 ^= x0;
  x0 += x1; x1 = rotl32(x1, 26); x1 ^= x0;
  x0 += x1; x1 = rotl32(x1,  6); x1 ^= x0;
  x0 += ks2; x1 += ks0 + 5u;
  return {x0, x1};
}

// ---- compile-time key derivation (jax.random.key(42) == (0,42)) -----------
constexpr TFPair KM = tf2x32(0u, 42u, 0u, 0u);   // kmask = split(key)[0]
constexpr TFPair KP = tf2x32(0u, 42u, 0u, 1u);   // kperm = split(key)[1]
constexpr TFPair C2 = tf2x32(KM.a, KM.b, 0u, 1u);   // k2 of split(kmask)
constexpr uint32_t KLO0 = C2.a, KLO1 = C2.b;
constexpr TFPair SB = tf2x32(KP.a, KP.b, 0u, 1u);   // subkey of split(kperm)
constexpr uint32_t KSUB0 = SB.a, KSUB1 = SB.b;

// ---- compile-time permutation: inv_perm[m] = stable rank of sortkey[m] ----
struct Keys { uint32_t v[NC]; };
constexpr Keys make_keys() {
  Keys k{};
  for (int i = 0; i < NC; ++i) {
    TFPair r = tf2x32(KSUB0, KSUB1, 0u, (uint32_t)i);
    k.v[i] = r.a ^ r.b;          // 32-bit random_bits, partitionable: hi^lo
  }
  return k;
}
constexpr Keys KEYS = make_keys();

#define PART_SZ 33
struct Part { int v[PART_SZ]; };
constexpr Part make_part(int lo) {
  Part p{};
  for (int m = lo; m < lo + PART_SZ && m < NC; ++m) {
    uint32_t km = KEYS.v[m];
    int rank = 0;
    for (int j = 0; j < NC; ++j) {
      uint32_t kj = KEYS.v[j];
      if (kj < km || (kj == km && j < m)) ++rank;
    }
    p.v[m - lo] = rank;
  }
  return p;
}
// 16 separate constexpr variables: each gets its own constexpr step budget.
constexpr Part PT0  = make_part(0),   PT1  = make_part(33),
               PT2  = make_part(66),  PT3  = make_part(99),
               PT4  = make_part(132), PT5  = make_part(165),
               PT6  = make_part(198), PT7  = make_part(231),
               PT8  = make_part(264), PT9  = make_part(297),
               PT10 = make_part(330), PT11 = make_part(363),
               PT12 = make_part(396), PT13 = make_part(429),
               PT14 = make_part(462), PT15 = make_part(495);

struct IPerm { int v[NC]; };
constexpr IPerm merge_parts() {
  IPerm r{};
  const Part* ps[16] = {&PT0, &PT1, &PT2,  &PT3,  &PT4,  &PT5,  &PT6,  &PT7,
                        &PT8, &PT9, &PT10, &PT11, &PT12, &PT13, &PT14, &PT15};
  for (int c = 0; c < 16; ++c)
    for (int i = 0; i < PART_SZ; ++i) {
      int m = c * PART_SZ + i;
      if (m < NC) r.v[m] = ps[c]->v[i];
    }
  return r;
}
constexpr IPerm IPERM = merge_parts();
constexpr int C_ORI = IPERM.v[256];     // output channel of the 'ori' column

// Packed channel-pair table: low16 = channel of +result (j), high16 = channel
// of -result (j+257).  Indexed by j = jl*16 + jj.
struct CTab { uint32_t v[256]; };
constexpr CTab make_ctab() {
  CTab c{};
  for (int j = 0; j < 256; ++j)
    c.v[j] = (uint32_t)IPERM.v[j] | ((uint32_t)IPERM.v[j + 257] << 16);
  return c;
}
constexpr CTab CTAB = make_ctab();
__device__ __constant__ CTab d_ctab = CTAB;

// ---- dist kernel: one block per t-row, 256 threads = 16 tp x 16 jl --------
__global__ __launch_bounds__(256, 4) void dist_kernel(
    const int* __restrict__ locations, const int* __restrict__ pos_idx,
    const float* __restrict__ norm, float* __restrict__ out) {
  __shared__ __align__(16) float buf[NC * TP_];   // 513*16 floats = 32832 B

  const int t   = (int)blockIdx.x;
  const int tid = (int)threadIdx.x;
  const int tp  = tid & 15;
  const int jl  = tid >> 4;                 // == h for all 16 j's of this thread

  const int   ori  = locations[pos_idx[t] * TP_ + tp];
  const float nm   = norm[t];
  const float nm16 = nm * 0.0625f;

  // the 'ori' channel: dist(ori,ori) = (1 - 1/16)*norm
  if (tid < 16) buf[C_ORI * TP_ + tid] = 0.9375f * nm;

  // per-thread packed channel pairs (statically indexed -> registers)
  uint32_t ct[16];
#pragma unroll
  for (int i = 0; i < 16; ++i) ct[i] = d_ctab.v[(jl << 4) + i];

  // hoisted per-thread constants (h == jl)
  const uint32_t flip_h = 1u << jl;
  const uint32_t mask_h = flip_h - 1u;
  const uint32_t base   = (uint32_t)(((jl * T_ + t) * K_) * TP_ + tp);
  const uint32_t ao     = (uint32_t)(ori < 0 ? -ori : ori);

#pragma unroll
  for (int jj = 0; jj < 16; ++jj) {
    // flat index into (H, T, K, TP) mask tensor; k == jj
    const TFPair r = tf2x32(KLO0, KLO1, 0u, base + (uint32_t)(jj * TP_));
    // flip bit h, xor the (2^h-1)-masked random bits
    const uint32_t fm = flip_h ^ (r.b & mask_h);
    const int v = ori ^ (int)fm;

    // dist(v, ori) = sign(v)*sign(ori) * (1 - bitlen(|v|^|ori|+1)/16) * norm
    const uint32_t sgbit = ((uint32_t)(v ^ ori)) & 0x80000000u;
    const uint32_t av = (uint32_t)(v < 0 ? -v : v);
    const uint32_t x  = (av ^ ao) + 1u;                  // <= 2^16, exact f32
    const int e = 32 - __clz((int)x);                    // bit length
    const float f  = nm - (float)e * nm16;               // (1 - e/16)*nm
    const float d1 = __uint_as_float(__float_as_uint(f) ^ sgbit);
    // dist(-v, ori): |v| unchanged, sign flips unless v==0
    const float d2 = (v == 0) ? d1
                   : __uint_as_float(__float_as_uint(d1) ^ 0x80000000u);

    const uint32_t pr = ct[jj];
    buf[(pr & 0xffffu) * TP_ + tp] = d1;
    buf[(pr >> 16)     * TP_ + tp] = d2;
  }

  __syncthreads();

  // stream the whole 32.8 KB row out, fully coalesced, write-once
  const f32x4* __restrict__ b4 = (const f32x4*)buf;
  f32x4* __restrict__ o4 = (f32x4*)(out + (size_t)t * (NC * TP_));
#pragma unroll
  for (int it = 0; it < 8; ++it)
    __builtin_nontemporal_store(b4[(it << 8) + tid], o4 + (it << 8) + tid);
  if (tid < 4)                                           // 2052 = 8*256 + 4
    __builtin_nontemporal_store(b4[2048 + tid], o4 + 2048 + tid);
}

extern "C" void kernel_launch(void* const* d_in, const int* in_sizes, int n_in,
                              void* d_out, int out_size, void* d_ws, size_t ws_size,
                              hipStream_t stream) {
  const int*   locations = (const int*)d_in[0];
  const int*   pos_idx   = (const int*)d_in[1];
  const float* norm      = (const float*)d_in[2];
  float* out = (float*)d_out;

  // MEASUREMENT: launch twice (idempotent). dur_us_new - 116.95 == true
  // per-launch kernel time K; OH = 116.95 - K is fixed harness overhead.
  hipLaunchKernelGGL(dist_kernel, dim3(T_), dim3(256), 0, stream,
                     locations, pos_idx, norm, out);
  hipLaunchKernelGGL(dist_kernel, dim3(T_), dim3(256), 0, stream,
                     locations, pos_idx, norm, out);
}

// Round 5
// 117.966 us; speedup vs baseline: 1.1624x; 1.1624x over previous
//
#include <hip/hip_runtime.h>
#include <stdint.h>

// ---------------------------------------------------------------------------
// CritiGraph distance kernel: bit-exact reproduction of the JAX reference
// (jax_threefry_partitionable=True path, verified absmax 0.0).
//
// Round-6 structure (persistent pipelined blocks) — resubmitted unchanged
// after a GPU-acquisition timeout:
//   Measurement (round 5, double-launch): K = 20.2 us kernel, 96.7 us fixed
//   harness overhead. K ~= compute(7.7) + store-drain(10.3) serialized,
//   because the single-row block hits endpgm right after its store burst and
//   __syncthreads drains vmcnt(0). This version overlaps them:
//   - Grid 512, each block processes 4 consecutive t-rows (2 blocks/CU).
//   - Single 32.8 KB LDS buffer per block; per row:
//       compute/scatter -> [lgkmcnt(0); s_barrier] -> ds_read + NT-store
//       issue -> [s_barrier] -> next row's compute overwrites the buffer
//     Raw s_barrier (NOT __syncthreads) so in-flight nontemporal stores are
//     never drained at a barrier; row i's stores retire under row i+1's
//     threefry compute. Only the last row's drain is end-exposed.
//   - Next row's ori/norm gather rotation-prefetched at loop top (latency
//     hidden under current row's compute). Row loop kept rolled
//     (#pragma unroll 1) so code fits I-cache; all per-jj state is
//     statically indexed (no scratch).
// ---------------------------------------------------------------------------

#define H_   16
#define TP_  16
#define K_   16
#define T_   2048
#define NC   513                       // 2*H*K + 1
#define ROWS 4
#define GRID (T_ / ROWS)               // 512 blocks, 2 per CU

typedef float f32x4 __attribute__((ext_vector_type(4)));

struct TFPair { uint32_t a, b; };

__host__ __device__ constexpr uint32_t rotl32(uint32_t x, int r) {
  return (x << r) | (x >> (32 - r));
}

__host__ __device__ constexpr TFPair tf2x32(uint32_t k0, uint32_t k1,
                                            uint32_t x0, uint32_t x1) {
  uint32_t ks0 = k0, ks1 = k1, ks2 = k0 ^ k1 ^ 0x1BD11BDAu;
  x0 += ks0; x1 += ks1;
  x0 += x1; x1 = rotl32(x1, 13); x1 ^= x0;
  x0 += x1; x1 = rotl32(x1, 15); x1 ^= x0;
  x0 += x1; x1 = rotl32(x1, 26); x1 ^= x0;
  x0 += x1; x1 = rotl32(x1,  6); x1 ^= x0;
  x0 += ks1; x1 += ks2 + 1u;
  x0 += x1; x1 = rotl32(x1, 17); x1 ^= x0;
  x0 += x1; x1 = rotl32(x1, 29); x1 ^= x0;
  x0 += x1; x1 = rotl32(x1, 16); x1 ^= x0;
  x0 += x1; x1 = rotl32(x1, 24); x1 ^= x0;
  x0 += ks2; x1 += ks0 + 2u;
  x0 += x1; x1 = rotl32(x1, 13); x1 ^= x0;
  x0 += x1; x1 = rotl32(x1, 15); x1 ^= x0;
  x0 += x1; x1 = rotl32(x1, 26); x1 ^= x0;
  x0 += x1; x1 = rotl32(x1,  6); x1 ^= x0;
  x0 += ks0; x1 += ks1 + 3u;
  x0 += x1; x1 = rotl32(x1, 17); x1 ^= x0;
  x0 += x1; x1 = rotl32(x1, 29); x1 ^= x0;
  x0 += x1; x1 = rotl32(x1, 16); x1 ^= x0;
  x0 += x1; x1 = rotl32(x1, 24); x1 ^= x0;
  x0 += ks1; x1 += ks2 + 4u;
  x0 += x1; x1 = rotl32(x1, 13); x1 ^= x0;
  x0 += x1; x1 = rotl32(x1, 15); x1 ^= x0;
  x0 += x1; x1 = rotl32(x1, 26); x1 ^= x0;
  x0 += x1; x1 = rotl32(x1,  6); x1 ^= x0;
  x0 += ks2; x1 += ks0 + 5u;
  return {x0, x1};
}

// ---- compile-time key derivation (jax.random.key(42) == (0,42)) -----------
constexpr TFPair KM = tf2x32(0u, 42u, 0u, 0u);   // kmask = split(key)[0]
constexpr TFPair KP = tf2x32(0u, 42u, 0u, 1u);   // kperm = split(key)[1]
constexpr TFPair C2 = tf2x32(KM.a, KM.b, 0u, 1u);   // k2 of split(kmask)
constexpr uint32_t KLO0 = C2.a, KLO1 = C2.b;
constexpr TFPair SB = tf2x32(KP.a, KP.b, 0u, 1u);   // subkey of split(kperm)
constexpr uint32_t KSUB0 = SB.a, KSUB1 = SB.b;

// ---- compile-time permutation: inv_perm[m] = stable rank of sortkey[m] ----
struct Keys { uint32_t v[NC]; };
constexpr Keys make_keys() {
  Keys k{};
  for (int i = 0; i < NC; ++i) {
    TFPair r = tf2x32(KSUB0, KSUB1, 0u, (uint32_t)i);
    k.v[i] = r.a ^ r.b;          // 32-bit random_bits, partitionable: hi^lo
  }
  return k;
}
constexpr Keys KEYS = make_keys();

#define PART_SZ 33
struct Part { int v[PART_SZ]; };
constexpr Part make_part(int lo) {
  Part p{};
  for (int m = lo; m < lo + PART_SZ && m < NC; ++m) {
    uint32_t km = KEYS.v[m];
    int rank = 0;
    for (int j = 0; j < NC; ++j) {
      uint32_t kj = KEYS.v[j];
      if (kj < km || (kj == km && j < m)) ++rank;
    }
    p.v[m - lo] = rank;
  }
  return p;
}
// 16 separate constexpr variables: each gets its own constexpr step budget.
constexpr Part PT0  = make_part(0),   PT1  = make_part(33),
               PT2  = make_part(66),  PT3  = make_part(99),
               PT4  = make_part(132), PT5  = make_part(165),
               PT6  = make_part(198), PT7  = make_part(231),
               PT8  = make_part(264), PT9  = make_part(297),
               PT10 = make_part(330), PT11 = make_part(363),
               PT12 = make_part(396), PT13 = make_part(429),
               PT14 = make_part(462), PT15 = make_part(495);

struct IPerm { int v[NC]; };
constexpr IPerm merge_parts() {
  IPerm r{};
  const Part* ps[16] = {&PT0, &PT1, &PT2,  &PT3,  &PT4,  &PT5,  &PT6,  &PT7,
                        &PT8, &PT9, &PT10, &PT11, &PT12, &PT13, &PT14, &PT15};
  for (int c = 0; c < 16; ++c)
    for (int i = 0; i < PART_SZ; ++i) {
      int m = c * PART_SZ + i;
      if (m < NC) r.v[m] = ps[c]->v[i];
    }
  return r;
}
constexpr IPerm IPERM = merge_parts();
constexpr int C_ORI = IPERM.v[256];     // output channel of the 'ori' column

// Packed channel-pair table: low16 = channel of +result (j), high16 = channel
// of -result (j+257).  Indexed by j = jl*16 + jj.
struct CTab { uint32_t v[256]; };
constexpr CTab make_ctab() {
  CTab c{};
  for (int j = 0; j < 256; ++j)
    c.v[j] = (uint32_t)IPERM.v[j] | ((uint32_t)IPERM.v[j + 257] << 16);
  return c;
}
constexpr CTab CTAB = make_ctab();
__device__ __constant__ CTab d_ctab = CTAB;

// ---- dist kernel: 512 persistent blocks x 4 rows, 256 thr = 16tp x 16jl ---
__global__ __launch_bounds__(256, 4) void dist_kernel(
    const int* __restrict__ locations, const int* __restrict__ pos_idx,
    const float* __restrict__ norm, float* __restrict__ out) {
  __shared__ __align__(16) float buf[NC * TP_];   // 513*16 floats = 32832 B

  const int tid = (int)threadIdx.x;
  const int tp  = tid & 15;
  const int jl  = tid >> 4;                 // == h for this thread's 16 j's
  const int t0  = (int)blockIdx.x * ROWS;

  // per-thread packed channel pairs (statically indexed -> registers)
  uint32_t ct[16];
#pragma unroll
  for (int i = 0; i < 16; ++i) ct[i] = d_ctab.v[(jl << 4) + i];

  const uint32_t flip_h = 1u << jl;
  const uint32_t mask_h = flip_h - 1u;
  const f32x4* __restrict__ b4 = (const f32x4*)buf;

  // rotation-prefetch of the first row's gather
  int   ori_c = locations[pos_idx[t0] * TP_ + tp];
  float nm_c  = norm[t0];

#pragma unroll 1
  for (int row = 0; row < ROWS; ++row) {
    const int t = t0 + row;

    // issue next row's gather early; retires under this row's compute
    int ori_n = 0; float nm_n = 0.0f;
    if (row + 1 < ROWS) {
      ori_n = locations[pos_idx[t + 1] * TP_ + tp];
      nm_n  = norm[t + 1];
    }

    const int   ori  = ori_c;
    const float nm   = nm_c;
    const float nm16 = nm * 0.0625f;
    const uint32_t ao   = (uint32_t)(ori < 0 ? -ori : ori);
    const uint32_t base = (uint32_t)(((jl * T_ + t) * K_) * TP_ + tp);

    // the 'ori' channel: dist(ori,ori) = (1 - 1/16)*norm
    if (tid < 16) buf[C_ORI * TP_ + tid] = 0.9375f * nm;

#pragma unroll
    for (int jj = 0; jj < 16; ++jj) {
      // flat index into (H, T, K, TP) mask tensor; k == jj
      const TFPair r = tf2x32(KLO0, KLO1, 0u, base + (uint32_t)(jj * TP_));
      // flip bit h, xor the (2^h-1)-masked random bits
      const uint32_t fm = flip_h ^ (r.b & mask_h);
      const int v = ori ^ (int)fm;

      // dist(v,ori) = sign(v)*sign(ori) * (1 - bitlen(|v|^|ori|+1)/16) * norm
      const uint32_t sgbit = ((uint32_t)(v ^ ori)) & 0x80000000u;
      const uint32_t av = (uint32_t)(v < 0 ? -v : v);
      const uint32_t x  = (av ^ ao) + 1u;                // <= 2^16, exact f32
      const int e = 32 - __clz((int)x);                  // bit length
      const float f  = nm - (float)e * nm16;             // (1 - e/16)*nm
      const float d1 = __uint_as_float(__float_as_uint(f) ^ sgbit);
      // dist(-v, ori): |v| unchanged, sign flips unless v==0
      const float d2 = (v == 0) ? d1
                     : __uint_as_float(__float_as_uint(d1) ^ 0x80000000u);

      const uint32_t pr = ct[jj];
      buf[(pr & 0xffffu) * TP_ + tp] = d1;
      buf[(pr >> 16)     * TP_ + tp] = d2;
    }

    // B1: all LDS scatter-writes visible; do NOT drain vmcnt (in-flight
    // nontemporal stores of the previous row keep retiring).
    __builtin_amdgcn_sched_barrier(0);
    asm volatile("s_waitcnt lgkmcnt(0)" ::: "memory");
    __builtin_amdgcn_s_barrier();
    __builtin_amdgcn_sched_barrier(0);

    // stream this row out: coalesced 16B nontemporal stores (full lines)
    f32x4* __restrict__ o4 = (f32x4*)(out + (size_t)t * (NC * TP_));
#pragma unroll
    for (int it = 0; it < 8; ++it)
      __builtin_nontemporal_store(b4[(it << 8) + tid], o4 + (it << 8) + tid);
    if (tid < 4)                                         // 2052 = 8*256 + 4
      __builtin_nontemporal_store(b4[2048 + tid], o4 + 2048 + tid);

    // B2: every thread's ds_reads are consumed (store issue forces the
    // lgkmcnt wait), so after this barrier the buffer is safely reusable.
    __builtin_amdgcn_sched_barrier(0);
    asm volatile("" ::: "memory");
    __builtin_amdgcn_s_barrier();
    __builtin_amdgcn_sched_barrier(0);

    ori_c = ori_n; nm_c = nm_n;
  }
}

extern "C" void kernel_launch(void* const* d_in, const int* in_sizes, int n_in,
                              void* d_out, int out_size, void* d_ws, size_t ws_size,
                              hipStream_t stream) {
  const int*   locations = (const int*)d_in[0];
  const int*   pos_idx   = (const int*)d_in[1];
  const float* norm      = (const float*)d_in[2];
  float* out = (float*)d_out;

  hipLaunchKernelGGL(dist_kernel, dim3(GRID), dim3(256), 0, stream,
                     locations, pos_idx, norm, out);
}

// Round 8
// 117.850 us; speedup vs baseline: 1.1636x; 1.0010x over previous
//
#include <hip/hip_runtime.h>
#include <stdint.h>

// ---------------------------------------------------------------------------
// CritiGraph distance kernel: bit-exact reproduction of the JAX reference
// (jax_threefry_partitionable=True path, verified absmax 0.0).
//
// Round-7 structure (register-staged, store-issue interleaved with compute)
// — resubmitted unchanged after GPU-acquisition timeouts:
//   Evidence: K(round4, 1-row blocks) = 20.2 us; K(round5, persistent +
//   barrier pipeline) = 21.3 us; compute(9.6) + store-drain(10.7) = 20.3 ->
//   compute and stores are fully SERIALIZED in both. Mechanism: the 32.8 KB
//   NT-store burst overruns the write queue, the storing wave stalls, and
//   the barrier right after the burst propagates the stall to all compute.
//   Fix: no barrier after store issue. Per row:
//     compute+scatter (interleaving the PREVIOUS row's 8 NT stores, one per
//     2 jj, from registers) -> [lgkmcnt(0); s_barrier] -> ds_read row into
//     8 f32x4 regs (+ tail by tid<4, stored immediately) -> [lgkmcnt(0);
//     s_barrier] -> buffer free, next row.
//   Stores spread across a whole row's compute ~= drain rate; a backpressure
//   stall delays one wave only, never a barrier. Only the last row's stores
//   + completion fence are exposed (~2.7 us/CU).
//   Grid 512 x ROWS=4 (2 blocks/CU), launch_bounds(256,2) for the 32-VGPR
//   staging array.
// ---------------------------------------------------------------------------

#define H_   16
#define TP_  16
#define K_   16
#define T_   2048
#define NC   513                       // 2*H*K + 1
#define ROWS 4
#define GRID (T_ / ROWS)               // 512 blocks, 2 per CU

typedef float f32x4 __attribute__((ext_vector_type(4)));

struct TFPair { uint32_t a, b; };

__host__ __device__ constexpr uint32_t rotl32(uint32_t x, int r) {
  return (x << r) | (x >> (32 - r));
}

__host__ __device__ constexpr TFPair tf2x32(uint32_t k0, uint32_t k1,
                                            uint32_t x0, uint32_t x1) {
  uint32_t ks0 = k0, ks1 = k1, ks2 = k0 ^ k1 ^ 0x1BD11BDAu;
  x0 += ks0; x1 += ks1;
  x0 += x1; x1 = rotl32(x1, 13); x1 ^= x0;
  x0 += x1; x1 = rotl32(x1, 15); x1 ^= x0;
  x0 += x1; x1 = rotl32(x1, 26); x1 ^= x0;
  x0 += x1; x1 = rotl32(x1,  6); x1 ^= x0;
  x0 += ks1; x1 += ks2 + 1u;
  x0 += x1; x1 = rotl32(x1, 17); x1 ^= x0;
  x0 += x1; x1 = rotl32(x1, 29); x1 ^= x0;
  x0 += x1; x1 = rotl32(x1, 16); x1 ^= x0;
  x0 += x1; x1 = rotl32(x1, 24); x1 ^= x0;
  x0 += ks2; x1 += ks0 + 2u;
  x0 += x1; x1 = rotl32(x1, 13); x1 ^= x0;
  x0 += x1; x1 = rotl32(x1, 15); x1 ^= x0;
  x0 += x1; x1 = rotl32(x1, 26); x1 ^= x0;
  x0 += x1; x1 = rotl32(x1,  6); x1 ^= x0;
  x0 += ks0; x1 += ks1 + 3u;
  x0 += x1; x1 = rotl32(x1, 17); x1 ^= x0;
  x0 += x1; x1 = rotl32(x1, 29); x1 ^= x0;
  x0 += x1; x1 = rotl32(x1, 16); x1 ^= x0;
  x0 += x1; x1 = rotl32(x1, 24); x1 ^= x0;
  x0 += ks1; x1 += ks2 + 4u;
  x0 += x1; x1 = rotl32(x1, 13); x1 ^= x0;
  x0 += x1; x1 = rotl32(x1, 15); x1 ^= x0;
  x0 += x1; x1 = rotl32(x1, 26); x1 ^= x0;
  x0 += x1; x1 = rotl32(x1,  6); x1 ^= x0;
  x0 += ks2; x1 += ks0 + 5u;
  return {x0, x1};
}

// ---- compile-time key derivation (jax.random.key(42) == (0,42)) -----------
constexpr TFPair KM = tf2x32(0u, 42u, 0u, 0u);   // kmask = split(key)[0]
constexpr TFPair KP = tf2x32(0u, 42u, 0u, 1u);   // kperm = split(key)[1]
constexpr TFPair C2 = tf2x32(KM.a, KM.b, 0u, 1u);   // k2 of split(kmask)
constexpr uint32_t KLO0 = C2.a, KLO1 = C2.b;
constexpr TFPair SB = tf2x32(KP.a, KP.b, 0u, 1u);   // subkey of split(kperm)
constexpr uint32_t KSUB0 = SB.a, KSUB1 = SB.b;

// ---- compile-time permutation: inv_perm[m] = stable rank of sortkey[m] ----
struct Keys { uint32_t v[NC]; };
constexpr Keys make_keys() {
  Keys k{};
  for (int i = 0; i < NC; ++i) {
    TFPair r = tf2x32(KSUB0, KSUB1, 0u, (uint32_t)i);
    k.v[i] = r.a ^ r.b;          // 32-bit random_bits, partitionable: hi^lo
  }
  return k;
}
constexpr Keys KEYS = make_keys();

#define PART_SZ 33
struct Part { int v[PART_SZ]; };
constexpr Part make_part(int lo) {
  Part p{};
  for (int m = lo; m < lo + PART_SZ && m < NC; ++m) {
    uint32_t km = KEYS.v[m];
    int rank = 0;
    for (int j = 0; j < NC; ++j) {
      uint32_t kj = KEYS.v[j];
      if (kj < km || (kj == km && j < m)) ++rank;
    }
    p.v[m - lo] = rank;
  }
  return p;
}
// 16 separate constexpr variables: each gets its own constexpr step budget.
constexpr Part PT0  = make_part(0),   PT1  = make_part(33),
               PT2  = make_part(66),  PT3  = make_part(99),
               PT4  = make_part(132), PT5  = make_part(165),
               PT6  = make_part(198), PT7  = make_part(231),
               PT8  = make_part(264), PT9  = make_part(297),
               PT10 = make_part(330), PT11 = make_part(363),
               PT12 = make_part(396), PT13 = make_part(429),
               PT14 = make_part(462), PT15 = make_part(495);

struct IPerm { int v[NC]; };
constexpr IPerm merge_parts() {
  IPerm r{};
  const Part* ps[16] = {&PT0, &PT1, &PT2,  &PT3,  &PT4,  &PT5,  &PT6,  &PT7,
                        &PT8, &PT9, &PT10, &PT11, &PT12, &PT13, &PT14, &PT15};
  for (int c = 0; c < 16; ++c)
    for (int i = 0; i < PART_SZ; ++i) {
      int m = c * PART_SZ + i;
      if (m < NC) r.v[m] = ps[c]->v[i];
    }
  return r;
}
constexpr IPerm IPERM = merge_parts();
constexpr int C_ORI = IPERM.v[256];     // output channel of the 'ori' column

// Packed channel-pair table: low16 = channel of +result (j), high16 = channel
// of -result (j+257).  Indexed by j = jl*16 + jj.
struct CTab { uint32_t v[256]; };
constexpr CTab make_ctab() {
  CTab c{};
  for (int j = 0; j < 256; ++j)
    c.v[j] = (uint32_t)IPERM.v[j] | ((uint32_t)IPERM.v[j + 257] << 16);
  return c;
}
constexpr CTab CTAB = make_ctab();
__device__ __constant__ CTab d_ctab = CTAB;

__device__ __forceinline__ void sbar_lgkm() {
  __builtin_amdgcn_sched_barrier(0);
  asm volatile("s_waitcnt lgkmcnt(0)" ::: "memory");
  __builtin_amdgcn_s_barrier();
  __builtin_amdgcn_sched_barrier(0);
}

// Compute one t-row into the LDS buffer. If DO_ST, interleave the previous
// row's 8 NT stores (from the stg registers) one per 2 jj iterations.
template <bool DO_ST>
__device__ __forceinline__ void compute_row(
    int ori, float nm, uint32_t base, uint32_t flip_h, uint32_t mask_h,
    const uint32_t* __restrict__ ct, float* __restrict__ buf,
    int tid, int tp, const f32x4* __restrict__ stg, f32x4* __restrict__ o4p) {
  const float nm16 = nm * 0.0625f;
  const uint32_t ao = (uint32_t)(ori < 0 ? -ori : ori);

  // the 'ori' channel: dist(ori,ori) = (1 - 1/16)*norm
  if (tid < 16) buf[C_ORI * TP_ + tid] = 0.9375f * nm;

#pragma unroll
  for (int jj = 0; jj < 16; ++jj) {
    // flat index into (H, T, K, TP) mask tensor; k == jj
    const TFPair r = tf2x32(KLO0, KLO1, 0u, base + (uint32_t)(jj * TP_));
    // flip bit h, xor the (2^h-1)-masked random bits
    const uint32_t fm = flip_h ^ (r.b & mask_h);
    const int v = ori ^ (int)fm;

    // dist(v,ori) = sign(v)*sign(ori) * (1 - bitlen(|v|^|ori|+1)/16) * norm
    const uint32_t sgbit = ((uint32_t)(v ^ ori)) & 0x80000000u;
    const uint32_t av = (uint32_t)(v < 0 ? -v : v);
    const uint32_t x  = (av ^ ao) + 1u;                // <= 2^16, exact f32
    const int e = 32 - __clz((int)x);                  // bit length
    const float f  = nm - (float)e * nm16;             // (1 - e/16)*nm
    const float d1 = __uint_as_float(__float_as_uint(f) ^ sgbit);
    // dist(-v, ori): |v| unchanged, sign flips unless v==0
    const float d2 = (v == 0) ? d1
                   : __uint_as_float(__float_as_uint(d1) ^ 0x80000000u);

    const uint32_t pr = ct[jj];
    buf[(pr & 0xffffu) * TP_ + tp] = d1;
    buf[(pr >> 16)     * TP_ + tp] = d2;

    if (DO_ST && (jj & 1)) {
      const int s = jj >> 1;                           // compile-time (unrolled)
      __builtin_nontemporal_store(stg[s], o4p + (s << 8) + tid);
      __builtin_amdgcn_sched_barrier(0);               // keep issue spread
    }
  }
}

// ---- dist kernel: 512 blocks x 4 rows, 256 thr = 16tp x 16jl --------------
__global__ __launch_bounds__(256, 2) void dist_kernel(
    const int* __restrict__ locations, const int* __restrict__ pos_idx,
    const float* __restrict__ norm, float* __restrict__ out) {
  __shared__ __align__(16) float buf[NC * TP_];   // 513*16 floats = 32832 B

  const int tid = (int)threadIdx.x;
  const int tp  = tid & 15;
  const int jl  = tid >> 4;                 // == h for this thread's 16 j's
  const int t0  = (int)blockIdx.x * ROWS;

  // per-thread packed channel pairs (statically indexed -> registers)
  uint32_t ct[16];
#pragma unroll
  for (int i = 0; i < 16; ++i) ct[i] = d_ctab.v[(jl << 4) + i];

  const uint32_t flip_h = 1u << jl;
  const uint32_t mask_h = flip_h - 1u;
  const f32x4* __restrict__ b4 = (const f32x4*)buf;

  f32x4 stg[8];                             // staged previous row (32 VGPR)

  // gathers: current row + rotation prefetch of the next
  int   ori_c = locations[pos_idx[t0] * TP_ + tp];
  float nm_c  = norm[t0];
  int   ori_n = locations[pos_idx[t0 + 1] * TP_ + tp];
  float nm_n  = norm[t0 + 1];

  // ---- peel row 0: compute only (nothing staged yet) ----------------------
  {
    const uint32_t base = (uint32_t)(((jl * T_ + t0) * K_) * TP_ + tp);
    compute_row<false>(ori_c, nm_c, base, flip_h, mask_h, ct, buf, tid, tp,
                       nullptr, nullptr);
    sbar_lgkm();                            // scatter visible
#pragma unroll
    for (int s = 0; s < 8; ++s) stg[s] = b4[(s << 8) + tid];
    if (tid < 4) {                          // tail: elements 2048..2051
      f32x4 tl = b4[2048 + tid];
      __builtin_nontemporal_store(
          tl, (f32x4*)(out + (size_t)t0 * (NC * TP_)) + 2048 + tid);
    }
    sbar_lgkm();                            // reads done -> buffer reusable
    ori_c = ori_n; nm_c = nm_n;
  }

  // ---- rows 1..ROWS-1: compute row r, interleave stores of row r-1 --------
#pragma unroll 1
  for (int row = 1; row < ROWS; ++row) {
    const int t = t0 + row;
    if (row + 1 < ROWS) {                   // prefetch next row's gather
      ori_n = locations[pos_idx[t + 1] * TP_ + tp];
      nm_n  = norm[t + 1];
    }

    f32x4* __restrict__ o4_prev = (f32x4*)(out + (size_t)(t - 1) * (NC * TP_));
    const uint32_t base = (uint32_t)(((jl * T_ + t) * K_) * TP_ + tp);
    compute_row<true>(ori_c, nm_c, base, flip_h, mask_h, ct, buf, tid, tp,
                      stg, o4_prev);

    sbar_lgkm();                            // scatter of row r visible
#pragma unroll
    for (int s = 0; s < 8; ++s) stg[s] = b4[(s << 8) + tid];
    if (tid < 4) {                          // tail of row r
      f32x4 tl = b4[2048 + tid];
      __builtin_nontemporal_store(
          tl, (f32x4*)(out + (size_t)t * (NC * TP_)) + 2048 + tid);
    }
    sbar_lgkm();                            // reads done -> buffer reusable
    ori_c = ori_n; nm_c = nm_n;
  }

  // ---- final burst: last row's main stores --------------------------------
  {
    f32x4* __restrict__ o4 =
        (f32x4*)(out + (size_t)(t0 + ROWS - 1) * (NC * TP_));
#pragma unroll
    for (int s = 0; s < 8; ++s)
      __builtin_nontemporal_store(stg[s], o4 + (s << 8) + tid);
  }
}

extern "C" void kernel_launch(void* const* d_in, const int* in_sizes, int n_in,
                              void* d_out, int out_size, void* d_ws, size_t ws_size,
                              hipStream_t stream) {
  const int*   locations = (const int*)d_in[0];
  const int*   pos_idx   = (const int*)d_in[1];
  const float* norm      = (const float*)d_in[2];
  float* out = (float*)d_out;

  hipLaunchKernelGGL(dist_kernel, dim3(GRID), dim3(256), 0, stream,
                     locations, pos_idx, norm, out);
}